// Round 11
// baseline (330.147 us; speedup 1.0000x reference)
//
#include <hip/hip_runtime.h>
#include <stdint.h>

typedef __attribute__((ext_vector_type(4))) float f32x4;
typedef __attribute__((ext_vector_type(8))) unsigned short u16x8;
typedef __attribute__((ext_vector_type(4))) unsigned short u16x4;
typedef unsigned short bf16_t;

#define DEV __device__ __forceinline__

// ---- MFMA 16x16x32 bf16 via inline asm (D = A*B + D) ----
DEV void mfma16(f32x4& d, u16x8 a, u16x8 b) {
    asm("v_mfma_f32_16x16x32_bf16 %0, %1, %2, %0" : "+v"(d) : "v"(a), "v"(b));
}

DEV bf16_t f2bf(float f) {
    uint32_t u = __builtin_bit_cast(uint32_t, f);
    return (bf16_t)((u + 0x7fffu + ((u >> 16) & 1u)) >> 16);
}

// async global->LDS, 16B per lane; lds dest is wave-uniform base (HW adds lane*16)
DEV void async_g2l16(const void* g, void* l) {
    __builtin_amdgcn_global_load_lds(
        (const __attribute__((address_space(1))) uint32_t*)(uintptr_t)g,
        (__attribute__((address_space(3))) uint32_t*)(uint32_t)(uintptr_t)l,
        16, 0, 0);
}

DEV void blockbar() {
    asm volatile("" ::: "memory");
    __builtin_amdgcn_s_barrier();
    asm volatile("" ::: "memory");
}

#define VMCNT(n) asm volatile("s_waitcnt vmcnt(" #n ")" ::: "memory")

// ======================= 256x256 / BK=64 NT GEMM (r7/r9 validated, unchanged) =======================
// EPI: 0 bf16; 1 bf16 relu(+bias); 2 f32 +res; 3 f32 +bias+res
template <int EPI>
__global__ __launch_bounds__(512, 2) void gemm256_nt(
    const bf16_t* __restrict__ A, const bf16_t* __restrict__ B,
    void* __restrict__ Cp, const float* __restrict__ bias,
    const float* __restrict__ res, int M, int N, int K)
{
    __shared__ bf16_t sA[2 * 16384];   // [2][256][64]
    __shared__ bf16_t sB[2 * 16384];
    const int tid = threadIdx.x;
    const int wave = tid >> 6, lane = tid & 63;
    const int lcol = lane & 15, krow = lane >> 4;
    const int wm = wave >> 2, wn = wave & 3;

    int id  = blockIdx.y * gridDim.x + blockIdx.x;
    int nwg = gridDim.x * gridDim.y;
    int swz = ((nwg & 7) == 0) ? ((id & 7) * (nwg >> 3) + (id >> 3)) : id;
    const int bn = swz % gridDim.y;
    const int bm = swz / gridDim.y;
    const int row_a = bm * 256, col_c = bn * 256;

    const int trow = tid >> 3;
    const int tr = (((tid & 7) ^ ((tid >> 3) & 7)) * 8);
    const bf16_t* aSt = A + (size_t)(row_a + trow) * K + tr;
    const bf16_t* bSt = B + (size_t)(col_c + trow) * K + tr;
    const size_t rstep = (size_t)64 * K;
    bf16_t* ldsAw = sA + wave * 512;
    bf16_t* ldsBw = sB + wave * 512;

    const int rowA = wm * 128 + lcol;
    const int rowB = wn * 64  + lcol;
    const int cA0 = ((krow ^ (rowA & 7))) * 8;
    const int cB0 = ((krow ^ (rowB & 7))) * 8;
    const int aBase = rowA * 64 + cA0;
    const int bBase = rowB * 64 + cB0;

    f32x4 acc[8][4] = {};
    const int nt = K >> 6;

#pragma unroll
    for (int i = 0; i < 4; i++) {
        async_g2l16(aSt + (size_t)i * rstep, ldsAw + i * 4096);
        async_g2l16(bSt + (size_t)i * rstep, ldsBw + i * 4096);
    }
    VMCNT(0);
    blockbar();

    for (int t = 0; t < nt; ++t) {
        const int rbase = (t & 1) ? 16384 : 0;
        const int wbase = 16384 - rbase;
        const bool pf = (t + 1) < nt;
        const size_t ko = (size_t)(t + 1) * 64;

        if (pf) {
#pragma unroll
            for (int i = 0; i < 4; i++) {
                async_g2l16(aSt + ko + (size_t)i * rstep, ldsAw + wbase + i * 4096);
                async_g2l16(bSt + ko + (size_t)i * rstep, ldsBw + wbase + i * 4096);
            }
        }

        u16x8 fa[8], fb[4];
#pragma unroll
        for (int mi = 0; mi < 8; mi++) fa[mi] = *(const u16x8*)&sA[rbase + aBase + mi * 1024];
#pragma unroll
        for (int ni = 0; ni < 4; ni++) fb[ni] = *(const u16x8*)&sB[rbase + bBase + ni * 1024];
#pragma unroll
        for (int mi = 0; mi < 8; mi++)
#pragma unroll
            for (int ni = 0; ni < 4; ni++)
                mfma16(acc[mi][ni], fa[mi], fb[ni]);
#pragma unroll
        for (int mi = 0; mi < 8; mi++) fa[mi] = *(const u16x8*)&sA[rbase + ((aBase + mi * 1024) ^ 32)];
#pragma unroll
        for (int ni = 0; ni < 4; ni++) fb[ni] = *(const u16x8*)&sB[rbase + ((bBase + ni * 1024) ^ 32)];
#pragma unroll
        for (int mi = 0; mi < 8; mi++)
#pragma unroll
            for (int ni = 0; ni < 4; ni++)
                mfma16(acc[mi][ni], fa[mi], fb[ni]);

        VMCNT(0);
        blockbar();
    }

#pragma unroll
    for (int mi = 0; mi < 8; mi++)
#pragma unroll
        for (int ni = 0; ni < 4; ni++)
#pragma unroll
            for (int j = 0; j < 4; j++) {
                const int gr = row_a + wm * 128 + mi * 16 + krow * 4 + j;
                const int gc = col_c + wn * 64 + ni * 16 + lcol;
                float v = acc[mi][ni][j];
                if (EPI == 0) {
                    ((bf16_t*)Cp)[(size_t)gr * N + gc] = f2bf(v);
                } else if (EPI == 1) {
                    v += bias[gc];
                    v = fmaxf(v, 0.f);
                    ((bf16_t*)Cp)[(size_t)gr * N + gc] = f2bf(v);
                } else if (EPI == 2) {
                    ((float*)Cp)[(size_t)gr * N + gc] = v + res[(size_t)gr * N + gc];
                } else {
                    ((float*)Cp)[(size_t)gr * N + gc] = v + bias[gc] + res[(size_t)gr * N + gc];
                }
            }
}

// ======================= 128x128 NT GEMM (qk proj, N=256) =======================
template <int EPI>
__global__ __launch_bounds__(256) void gemm_nt(
    const bf16_t* __restrict__ A, const bf16_t* __restrict__ B,
    void* __restrict__ Cp, const float* __restrict__ bias,
    const float* __restrict__ res, int M, int N, int K)
{
    alignas(16) __shared__ bf16_t sA[128 * 32];
    alignas(16) __shared__ bf16_t sB[128 * 32];
    const int tid = threadIdx.x;
    const int wave = tid >> 6, lane = tid & 63;
    const int lcol = lane & 15, krow = lane >> 4;

    int id  = blockIdx.y * gridDim.x + blockIdx.x;
    int nwg = gridDim.x * gridDim.y;
    int swz = ((nwg & 7) == 0) ? ((id & 7) * (nwg >> 3) + (id >> 3)) : id;
    const int bn = swz % gridDim.y;
    const int bm = swz / gridDim.y;

    const int row_a = bm * 128, col_c = bn * 128;
    const int wm = (wave >> 1) * 64, wn = (wave & 1) * 64;

    const int   srow  = wave * 16 + (lane >> 2);
    const int   scol  = (lane & 3) * 8;
    const bf16_t* aSrc = A + (size_t)(row_a + srow) * K + scol;
    const bf16_t* bSrc = B + (size_t)(col_c + srow) * K + scol;
    char* sAl = (char*)sA + wave * 1024;
    char* sBl = (char*)sB + wave * 1024;
    const size_t rstep = (size_t)64 * K;

    f32x4 acc[4][4] = {};

    for (int k0 = 0; k0 < K; k0 += 32) {
        async_g2l16(aSrc + k0,         sAl);
        async_g2l16(aSrc + k0 + rstep, sAl + 4096);
        async_g2l16(bSrc + k0,         sBl);
        async_g2l16(bSrc + k0 + rstep, sBl + 4096);
        __syncthreads();
        u16x8 af[4], bfr[4];
#pragma unroll
        for (int i = 0; i < 4; i++) {
            af[i]  = *(const u16x8*)&sA[(wm + i * 16 + lcol) * 32 + krow * 8];
            bfr[i] = *(const u16x8*)&sB[(wn + i * 16 + lcol) * 32 + krow * 8];
        }
#pragma unroll
        for (int mi = 0; mi < 4; mi++)
#pragma unroll
            for (int ni = 0; ni < 4; ni++)
                mfma16(acc[mi][ni], af[mi], bfr[ni]);
        __syncthreads();
    }

#pragma unroll
    for (int mi = 0; mi < 4; mi++)
#pragma unroll
        for (int ni = 0; ni < 4; ni++)
#pragma unroll
            for (int j = 0; j < 4; j++) {
                const int gr = row_a + wm + mi * 16 + krow * 4 + j;
                const int gc = col_c + wn + ni * 16 + lcol;
                float v = acc[mi][ni][j];
                if (EPI == 0) {
                    ((bf16_t*)Cp)[(size_t)gr * N + gc] = f2bf(v);
                } else if (EPI == 1) {
                    v += bias[gc];
                    v = fmaxf(v, 0.f);
                    ((bf16_t*)Cp)[(size_t)gr * N + gc] = f2bf(v);
                } else if (EPI == 2) {
                    ((float*)Cp)[(size_t)gr * N + gc] = v + res[(size_t)gr * N + gc];
                } else {
                    ((float*)Cp)[(size_t)gr * N + gc] = v + bias[gc] + res[(size_t)gr * N + gc];
                }
            }
}

// ======================= LayerNorm f32 -> bf16 (used for LN2) =======================
__global__ __launch_bounds__(256) void ln_kernel(
    const float* __restrict__ X, const float* __restrict__ G,
    const float* __restrict__ Bt, bf16_t* __restrict__ O)
{
    const int row = blockIdx.x, tid = threadIdx.x;
    const int wave = tid >> 6, lane = tid & 63;
    const size_t base = (size_t)row * 1024 + tid * 4;
    f32x4 xv = *(const f32x4*)&X[base];
    float s  = xv[0] + xv[1] + xv[2] + xv[3];
    float s2 = xv[0]*xv[0] + xv[1]*xv[1] + xv[2]*xv[2] + xv[3]*xv[3];
#pragma unroll
    for (int o = 1; o < 64; o <<= 1) { s += __shfl_xor(s, o); s2 += __shfl_xor(s2, o); }
    __shared__ float red[8];
    if (lane == 0) { red[wave] = s; red[wave + 4] = s2; }
    __syncthreads();
    s  = red[0] + red[1] + red[2] + red[3];
    s2 = red[4] + red[5] + red[6] + red[7];
    const float mu = s * (1.f / 1024.f);
    const float rs = rsqrtf(s2 * (1.f / 1024.f) - mu * mu + 1e-5f);
    f32x4 gv = *(const f32x4*)&G[tid * 4];
    f32x4 bv = *(const f32x4*)&Bt[tid * 4];
    u16x4 ov;
#pragma unroll
    for (int i = 0; i < 4; i++) ov[i] = f2bf((xv[i] - mu) * rs * gv[i] + bv[i]);
    *(u16x4*)&O[base] = ov;
}

// ======================= fused: weight cvt (blocks < ncvtblk) + LN1 (rest) =======================
// The two halves are fully independent (weights-only vs x-only); branch is uniform per block.
__global__ __launch_bounds__(256) void cvt_ln(
    const float* __restrict__ s0, const float* __restrict__ s1,
    const float* __restrict__ s2, const float* __restrict__ s3,
    const float* __restrict__ s4, bf16_t* __restrict__ wdst,
    int n0, int n1, int n2, int n3, int n4, int ncvtblk,
    const float* __restrict__ X, const float* __restrict__ G,
    const float* __restrict__ Bt, bf16_t* __restrict__ O)
{
    const int tid = threadIdx.x;
    if ((int)blockIdx.x < ncvtblk) {
        int i = (blockIdx.x * 256 + tid) * 4;
        const float* sp; int base;
        if (i < n0)                     { sp = s0; base = 0; }
        else if (i < n0+n1)             { sp = s1; base = n0; }
        else if (i < n0+n1+n2)          { sp = s2; base = n0+n1; }
        else if (i < n0+n1+n2+n3)       { sp = s3; base = n0+n1+n2; }
        else                            { sp = s4; base = n0+n1+n2+n3; }
        f32x4 v = *(const f32x4*)&sp[i - base];
        u16x4 o;
#pragma unroll
        for (int t = 0; t < 4; t++) o[t] = f2bf(v[t]);
        *(u16x4*)&wdst[i] = o;
        return;
    }
    const int row = blockIdx.x - ncvtblk;
    const int wave = tid >> 6, lane = tid & 63;
    const size_t base = (size_t)row * 1024 + tid * 4;
    f32x4 xv = *(const f32x4*)&X[base];
    float sum = xv[0] + xv[1] + xv[2] + xv[3];
    float ssq = xv[0]*xv[0] + xv[1]*xv[1] + xv[2]*xv[2] + xv[3]*xv[3];
#pragma unroll
    for (int o = 1; o < 64; o <<= 1) { sum += __shfl_xor(sum, o); ssq += __shfl_xor(ssq, o); }
    __shared__ float red[8];
    if (lane == 0) { red[wave] = sum; red[wave + 4] = ssq; }
    __syncthreads();
    sum = red[0] + red[1] + red[2] + red[3];
    ssq = red[4] + red[5] + red[6] + red[7];
    const float mu = sum * (1.f / 1024.f);
    const float rs = rsqrtf(ssq * (1.f / 1024.f) - mu * mu + 1e-5f);
    f32x4 gv = *(const f32x4*)&G[tid * 4];
    f32x4 bv = *(const f32x4*)&Bt[tid * 4];
    u16x4 ov;
#pragma unroll
    for (int i = 0; i < 4; i++) ov[i] = f2bf((xv[i] - mu) * rs * gv[i] + bv[i]);
    *(u16x4*)&O[base] = ov;
}

// ======================= banded softmax, window 256 (ALiBi + causal) — validated =======================
__global__ __launch_bounds__(256) void attn_p(
    const bf16_t* __restrict__ QK, bf16_t* __restrict__ P, int T)
{
    const int tid = threadIdx.x, w = tid >> 6, lane = tid & 63;
    const int lcol = lane & 15, krow = lane >> 4;
    const int qt = blockIdx.x;
    const int ntb = T >> 6;
    const int b = qt / ntb;
    const int r0 = (qt - b * ntb) << 6;
    const size_t g0 = (size_t)b * T + r0;
    const int jbase = r0 - 192;
    const float scale = 0.08838834764831845f;  // 128^-0.5

    __shared__ float lred[2][4][64];

    u16x8 qf[4][4];
#pragma unroll
    for (int mf = 0; mf < 4; mf++)
#pragma unroll
        for (int ks = 0; ks < 4; ks++)
            qf[mf][ks] = *(const u16x8*)&QK[(g0 + mf * 16 + lcol) * 256 + ks * 32 + krow * 8];

    f32x4 acc[4][4] = {};
    const size_t kbase = (size_t)b * T * 256 + 128;
#pragma unroll
    for (int ks = 0; ks < 4; ks++) {
        u16x8 kf[4];
#pragma unroll
        for (int nf = 0; nf < 4; nf++) {
            int jc = jbase + w * 64 + nf * 16 + lcol;
            int jr = jc < 0 ? 0 : jc;
            kf[nf] = *(const u16x8*)&QK[kbase + (size_t)jr * 256 + ks * 32 + krow * 8];
        }
#pragma unroll
        for (int mf = 0; mf < 4; mf++)
#pragma unroll
            for (int nf = 0; nf < 4; nf++)
                mfma16(acc[mf][nf], qf[mf][ks], kf[nf]);
    }

#pragma unroll
    for (int mf = 0; mf < 4; mf++)
#pragma unroll
        for (int j = 0; j < 4; j++) {
            const int i_ = r0 + mf * 16 + krow * 4 + j;
            float m = -1e30f;
#pragma unroll
            for (int nf = 0; nf < 4; nf++) {
                const int jc = jbase + w * 64 + nf * 16 + lcol;
                float sv = (jc >= 0 && jc <= i_) ? acc[mf][nf][j] * scale - (float)(i_ - jc) : -1e30f;
                acc[mf][nf][j] = sv;
                m = fmaxf(m, sv);
            }
#pragma unroll
            for (int o = 1; o < 16; o <<= 1) m = fmaxf(m, __shfl_xor(m, o));
            if (lcol == 0) lred[0][w][mf * 16 + krow * 4 + j] = m;
        }
    __syncthreads();

#pragma unroll
    for (int mf = 0; mf < 4; mf++)
#pragma unroll
        for (int j = 0; j < 4; j++) {
            const int rr = mf * 16 + krow * 4 + j;
            const float m = fmaxf(fmaxf(lred[0][0][rr], lred[0][1][rr]),
                                  fmaxf(lred[0][2][rr], lred[0][3][rr]));
            float sm = 0.f;
#pragma unroll
            for (int nf = 0; nf < 4; nf++) {
                float p = __expf(acc[mf][nf][j] - m);
                acc[mf][nf][j] = p;
                sm += p;
            }
#pragma unroll
            for (int o = 1; o < 16; o <<= 1) sm += __shfl_xor(sm, o);
            if (lcol == 0) lred[1][w][rr] = sm;
        }
    __syncthreads();

    float inv_l[4][4];
#pragma unroll
    for (int mf = 0; mf < 4; mf++)
#pragma unroll
        for (int j = 0; j < 4; j++) {
            const int rr = mf * 16 + krow * 4 + j;
            inv_l[mf][j] = 1.f / (lred[1][0][rr] + lred[1][1][rr] + lred[1][2][rr] + lred[1][3][rr]);
        }
#pragma unroll
    for (int mf = 0; mf < 4; mf++)
#pragma unroll
        for (int nf = 0; nf < 4; nf++)
#pragma unroll
            for (int j = 0; j < 4; j++) {
                const int rr = mf * 16 + krow * 4 + j;
                P[((size_t)qt * 64 + rr) * 256 + w * 64 + nf * 16 + lcol] =
                    f2bf(acc[mf][nf][j] * inv_l[mf][j]);
            }
}

// ======================= band PV2: x2 = x + P @ G  (G = h @ Wv^T, K=256 band) =======================
// Associativity swap: (P@H)@Wv^T == P@(H@Wv^T). Same structure as the validated
// pv_gemm with H->G and an f32 +residual epilogue (writes d_out directly).
__global__ __launch_bounds__(256) void pv2_gemm(
    const bf16_t* __restrict__ P, const bf16_t* __restrict__ Gm,
    const float* __restrict__ X, float* __restrict__ X2, int T)
{
    alignas(16) __shared__ bf16_t sHt[128 * 40];
    const int tid = threadIdx.x, w = tid >> 6, lane = tid & 63;
    const int lcol = lane & 15, krow = lane >> 4;
    const int qt = blockIdx.x, d0 = blockIdx.y * 128;
    const int ntb = T >> 6, b = qt / ntb;
    const int r0 = (qt - b * ntb) << 6;
    const int jbase = r0 - 192;
    const int wm = (w >> 1) * 32, wn = (w & 1) * 64;
    const int kk = tid >> 3, seg = tid & 7;

    f32x4 acc[2][4] = {};
    for (int k0 = 0; k0 < 256; k0 += 32) {
        int j = jbase + k0 + kk;
        if (j < 0) j = 0;  // P is 0 there
        const bf16_t* hp = Gm + ((size_t)b * T + j) * 1024 + d0 + seg * 16;
        u16x8 v0 = *(const u16x8*)hp;
        u16x8 v1 = *(const u16x8*)(hp + 8);
        __syncthreads();
#pragma unroll
        for (int i = 0; i < 8; i++) {
            sHt[(seg * 16 + i) * 40 + kk]     = v0[i];
            sHt[(seg * 16 + 8 + i) * 40 + kk] = v1[i];
        }
        __syncthreads();
        u16x8 af[2], bfr[4];
#pragma unroll
        for (int mi = 0; mi < 2; mi++)
            af[mi] = *(const u16x8*)&P[((size_t)qt * 64 + wm + mi * 16 + lcol) * 256 + k0 + krow * 8];
#pragma unroll
        for (int ni = 0; ni < 4; ni++)
            bfr[ni] = *(const u16x8*)&sHt[(wn + ni * 16 + lcol) * 40 + krow * 8];
#pragma unroll
        for (int mi = 0; mi < 2; mi++)
#pragma unroll
            for (int ni = 0; ni < 4; ni++)
                mfma16(acc[mi][ni], af[mi], bfr[ni]);
    }
#pragma unroll
    for (int mi = 0; mi < 2; mi++)
#pragma unroll
        for (int ni = 0; ni < 4; ni++)
#pragma unroll
            for (int j = 0; j < 4; j++) {
                const size_t oi = ((size_t)b * T + r0 + wm + mi * 16 + krow * 4 + j) * 1024 +
                                  d0 + wn + ni * 16 + lcol;
                X2[oi] = X[oi] + acc[mi][ni][j];
            }
}

// ======================= launch =======================
extern "C" void kernel_launch(void* const* d_in, const int* in_sizes, int n_in,
                              void* d_out, int out_size, void* d_ws, size_t ws_size,
                              hipStream_t stream)
{
    const float* x   = (const float*)d_in[0];
    const float* g1  = (const float*)d_in[1];
    const float* be1 = (const float*)d_in[2];
    const float* Wq  = (const float*)d_in[3];
    const float* Wk  = (const float*)d_in[4];
    const float* Wv  = (const float*)d_in[5];
    const float* g2  = (const float*)d_in[6];
    const float* be2 = (const float*)d_in[7];
    const float* W1  = (const float*)d_in[8];
    const float* b1  = (const float*)d_in[9];
    const float* W2  = (const float*)d_in[10];
    const float* b2  = (const float*)d_in[11];

    const int B = 4, T = 4096, D = 1024, DK = 128, F = 2048;
    const int BT = B * T;

    char* ws = (char*)d_ws;
    size_t off = 0;
    auto alloc = [&](size_t bytes) {
        void* p = ws + off;
        off += (bytes + 255) & ~(size_t)255;
        return p;
    };
    // NOTE: the 5 weight segments are contiguous; cvt half of cvt_ln writes them flat.
    bf16_t* wqk_b = (bf16_t*)alloc((size_t)2 * DK * D * 2);
    bf16_t* wv_b  = (bf16_t*)alloc((size_t)D * D * 2);
    bf16_t* w1_b  = (bf16_t*)alloc((size_t)F * D * 2);
    bf16_t* w2_b  = (bf16_t*)alloc((size_t)D * F * 2);
    bf16_t* h     = (bf16_t*)alloc((size_t)BT * D * 2);   // reused as h2
    bf16_t* qk    = (bf16_t*)alloc((size_t)BT * 256 * 2); // q | k
    bf16_t* P     = (bf16_t*)alloc((size_t)BT * 256 * 2); // window 256
    bf16_t* G     = (bf16_t*)alloc((size_t)BT * D * 2);   // h @ Wv^T
    bf16_t* ff    = (bf16_t*)alloc((size_t)BT * F * 2);
    if (ws_size < off) return;
    float* x2 = (float*)d_out;

    // fused: weight cvt + LN1  (independent halves, one launch)
    const int n0 = DK * D, n2 = D * D, n3 = F * D, n4 = D * F;
    const int ncvtblk = (n0 + n0 + n2 + n3 + n4) / 1024;   // 5376
    cvt_ln<<<ncvtblk + BT, 256, 0, stream>>>(Wq, Wk, Wv, W1, W2, wqk_b,
                                             n0, n0, n2, n3, n4, ncvtblk,
                                             x, g1, be1, h);

    // [q|k] = h @ [Wq;Wk]^T   (fused, N=256)
    gemm_nt<0><<<dim3(BT / 128, 2), 256, 0, stream>>>(h, wqk_b, qk, nullptr, nullptr, BT, 256, D);

    // G = h @ Wv^T   (associativity swap; replaces the old ctx @ Wv^T)
    gemm256_nt<0><<<dim3(BT / 256, D / 256), 512, 0, stream>>>(h, wv_b, G, nullptr, nullptr, BT, D, D);

    // banded softmax (window 256) -> P, then x2 = x + P @ G (f32, into d_out)
    attn_p<<<BT / 64, 256, 0, stream>>>(qk, P, T);
    pv2_gemm<<<dim3(BT / 64, D / 128), 256, 0, stream>>>(P, G, x, x2, T);

    // h2 = LN2(x2) (reuse h)
    ln_kernel<<<BT, 256, 0, stream>>>(x2, g2, be2, h);

    // ff = relu(h2 @ W1^T + b1)
    gemm256_nt<1><<<dim3(BT / 256, F / 256), 512, 0, stream>>>(h, w1_b, ff, b1, nullptr, BT, F, D);

    // out = x2 + ff @ W2^T + b2  (in-place on d_out)
    gemm256_nt<3><<<dim3(BT / 256, D / 256), 512, 0, stream>>>(ff, w2_b, x2, b2, x2, BT, D, F);
}

// Round 13
// 320.160 us; speedup vs baseline: 1.0312x; 1.0312x over previous
//
#include <hip/hip_runtime.h>
#include <stdint.h>

typedef __attribute__((ext_vector_type(4))) float f32x4;
typedef __attribute__((ext_vector_type(8))) unsigned short u16x8;
typedef __attribute__((ext_vector_type(4))) unsigned short u16x4;
typedef unsigned short bf16_t;

#define DEV __device__ __forceinline__

// ---- MFMA 16x16x32 bf16 via inline asm (D = A*B + D) ----
DEV void mfma16(f32x4& d, u16x8 a, u16x8 b) {
    asm("v_mfma_f32_16x16x32_bf16 %0, %1, %2, %0" : "+v"(d) : "v"(a), "v"(b));
}

DEV bf16_t f2bf(float f) {
    uint32_t u = __builtin_bit_cast(uint32_t, f);
    return (bf16_t)((u + 0x7fffu + ((u >> 16) & 1u)) >> 16);
}

// async global->LDS, 16B per lane; lds dest is wave-uniform base (HW adds lane*16)
DEV void async_g2l16(const void* g, void* l) {
    __builtin_amdgcn_global_load_lds(
        (const __attribute__((address_space(1))) uint32_t*)(uintptr_t)g,
        (__attribute__((address_space(3))) uint32_t*)(uint32_t)(uintptr_t)l,
        16, 0, 0);
}

DEV void blockbar() {
    asm volatile("" ::: "memory");
    __builtin_amdgcn_s_barrier();
    asm volatile("" ::: "memory");
}

#define VMCNT(n) asm volatile("s_waitcnt vmcnt(" #n ")" ::: "memory")

// ======================= 256x256 / BK=64 NT GEMM (r7/r9 validated, unchanged) =======================
// LDS-read-throughput-bound at ~30% MfmaUtil (192 ds_read_b128/CU/tile vs 620cy MFMA) — structural.
// EPI: 0 bf16; 1 bf16 relu(+bias); 2 f32 +res; 3 f32 +bias+res
template <int EPI>
__global__ __launch_bounds__(512, 2) void gemm256_nt(
    const bf16_t* __restrict__ A, const bf16_t* __restrict__ B,
    void* __restrict__ Cp, const float* __restrict__ bias,
    const float* __restrict__ res, int M, int N, int K)
{
    __shared__ bf16_t sA[2 * 16384];   // [2][256][64]
    __shared__ bf16_t sB[2 * 16384];
    const int tid = threadIdx.x;
    const int wave = tid >> 6, lane = tid & 63;
    const int lcol = lane & 15, krow = lane >> 4;
    const int wm = wave >> 2, wn = wave & 3;

    int id  = blockIdx.y * gridDim.x + blockIdx.x;
    int nwg = gridDim.x * gridDim.y;
    int swz = ((nwg & 7) == 0) ? ((id & 7) * (nwg >> 3) + (id >> 3)) : id;
    const int bn = swz % gridDim.y;
    const int bm = swz / gridDim.y;
    const int row_a = bm * 256, col_c = bn * 256;

    const int trow = tid >> 3;
    const int tr = (((tid & 7) ^ ((tid >> 3) & 7)) * 8);
    const bf16_t* aSt = A + (size_t)(row_a + trow) * K + tr;
    const bf16_t* bSt = B + (size_t)(col_c + trow) * K + tr;
    const size_t rstep = (size_t)64 * K;
    bf16_t* ldsAw = sA + wave * 512;
    bf16_t* ldsBw = sB + wave * 512;

    const int rowA = wm * 128 + lcol;
    const int rowB = wn * 64  + lcol;
    const int cA0 = ((krow ^ (rowA & 7))) * 8;
    const int cB0 = ((krow ^ (rowB & 7))) * 8;
    const int aBase = rowA * 64 + cA0;
    const int bBase = rowB * 64 + cB0;

    f32x4 acc[8][4] = {};
    const int nt = K >> 6;

#pragma unroll
    for (int i = 0; i < 4; i++) {
        async_g2l16(aSt + (size_t)i * rstep, ldsAw + i * 4096);
        async_g2l16(bSt + (size_t)i * rstep, ldsBw + i * 4096);
    }
    VMCNT(0);
    blockbar();

    for (int t = 0; t < nt; ++t) {
        const int rbase = (t & 1) ? 16384 : 0;
        const int wbase = 16384 - rbase;
        const bool pf = (t + 1) < nt;
        const size_t ko = (size_t)(t + 1) * 64;

        if (pf) {
#pragma unroll
            for (int i = 0; i < 4; i++) {
                async_g2l16(aSt + ko + (size_t)i * rstep, ldsAw + wbase + i * 4096);
                async_g2l16(bSt + ko + (size_t)i * rstep, ldsBw + wbase + i * 4096);
            }
        }

        u16x8 fa[8], fb[4];
#pragma unroll
        for (int mi = 0; mi < 8; mi++) fa[mi] = *(const u16x8*)&sA[rbase + aBase + mi * 1024];
#pragma unroll
        for (int ni = 0; ni < 4; ni++) fb[ni] = *(const u16x8*)&sB[rbase + bBase + ni * 1024];
#pragma unroll
        for (int mi = 0; mi < 8; mi++)
#pragma unroll
            for (int ni = 0; ni < 4; ni++)
                mfma16(acc[mi][ni], fa[mi], fb[ni]);
#pragma unroll
        for (int mi = 0; mi < 8; mi++) fa[mi] = *(const u16x8*)&sA[rbase + ((aBase + mi * 1024) ^ 32)];
#pragma unroll
        for (int ni = 0; ni < 4; ni++) fb[ni] = *(const u16x8*)&sB[rbase + ((bBase + ni * 1024) ^ 32)];
#pragma unroll
        for (int mi = 0; mi < 8; mi++)
#pragma unroll
            for (int ni = 0; ni < 4; ni++)
                mfma16(acc[mi][ni], fa[mi], fb[ni]);

        VMCNT(0);
        blockbar();
    }

#pragma unroll
    for (int mi = 0; mi < 8; mi++)
#pragma unroll
        for (int ni = 0; ni < 4; ni++)
#pragma unroll
            for (int j = 0; j < 4; j++) {
                const int gr = row_a + wm * 128 + mi * 16 + krow * 4 + j;
                const int gc = col_c + wn * 64 + ni * 16 + lcol;
                float v = acc[mi][ni][j];
                if (EPI == 0) {
                    ((bf16_t*)Cp)[(size_t)gr * N + gc] = f2bf(v);
                } else if (EPI == 1) {
                    v += bias[gc];
                    v = fmaxf(v, 0.f);
                    ((bf16_t*)Cp)[(size_t)gr * N + gc] = f2bf(v);
                } else if (EPI == 2) {
                    ((float*)Cp)[(size_t)gr * N + gc] = v + res[(size_t)gr * N + gc];
                } else {
                    ((float*)Cp)[(size_t)gr * N + gc] = v + bias[gc] + res[(size_t)gr * N + gc];
                }
            }
}

// ======================= 128x128 NT GEMM (qk proj, N=256) =======================
template <int EPI>
__global__ __launch_bounds__(256) void gemm_nt(
    const bf16_t* __restrict__ A, const bf16_t* __restrict__ B,
    void* __restrict__ Cp, const float* __restrict__ bias,
    const float* __restrict__ res, int M, int N, int K)
{
    alignas(16) __shared__ bf16_t sA[128 * 32];
    alignas(16) __shared__ bf16_t sB[128 * 32];
    const int tid = threadIdx.x;
    const int wave = tid >> 6, lane = tid & 63;
    const int lcol = lane & 15, krow = lane >> 4;

    int id  = blockIdx.y * gridDim.x + blockIdx.x;
    int nwg = gridDim.x * gridDim.y;
    int swz = ((nwg & 7) == 0) ? ((id & 7) * (nwg >> 3) + (id >> 3)) : id;
    const int bn = swz % gridDim.y;
    const int bm = swz / gridDim.y;

    const int row_a = bm * 128, col_c = bn * 128;
    const int wm = (wave >> 1) * 64, wn = (wave & 1) * 64;

    const int   srow  = wave * 16 + (lane >> 2);
    const int   scol  = (lane & 3) * 8;
    const bf16_t* aSrc = A + (size_t)(row_a + srow) * K + scol;
    const bf16_t* bSrc = B + (size_t)(col_c + srow) * K + scol;
    char* sAl = (char*)sA + wave * 1024;
    char* sBl = (char*)sB + wave * 1024;
    const size_t rstep = (size_t)64 * K;

    f32x4 acc[4][4] = {};

    for (int k0 = 0; k0 < K; k0 += 32) {
        async_g2l16(aSrc + k0,         sAl);
        async_g2l16(aSrc + k0 + rstep, sAl + 4096);
        async_g2l16(bSrc + k0,         sBl);
        async_g2l16(bSrc + k0 + rstep, sBl + 4096);
        __syncthreads();
        u16x8 af[4], bfr[4];
#pragma unroll
        for (int i = 0; i < 4; i++) {
            af[i]  = *(const u16x8*)&sA[(wm + i * 16 + lcol) * 32 + krow * 8];
            bfr[i] = *(const u16x8*)&sB[(wn + i * 16 + lcol) * 32 + krow * 8];
        }
#pragma unroll
        for (int mi = 0; mi < 4; mi++)
#pragma unroll
            for (int ni = 0; ni < 4; ni++)
                mfma16(acc[mi][ni], af[mi], bfr[ni]);
        __syncthreads();
    }

#pragma unroll
    for (int mi = 0; mi < 4; mi++)
#pragma unroll
        for (int ni = 0; ni < 4; ni++)
#pragma unroll
            for (int j = 0; j < 4; j++) {
                const int gr = row_a + wm + mi * 16 + krow * 4 + j;
                const int gc = col_c + wn + ni * 16 + lcol;
                float v = acc[mi][ni][j];
                if (EPI == 0) {
                    ((bf16_t*)Cp)[(size_t)gr * N + gc] = f2bf(v);
                } else if (EPI == 1) {
                    v += bias[gc];
                    v = fmaxf(v, 0.f);
                    ((bf16_t*)Cp)[(size_t)gr * N + gc] = f2bf(v);
                } else if (EPI == 2) {
                    ((float*)Cp)[(size_t)gr * N + gc] = v + res[(size_t)gr * N + gc];
                } else {
                    ((float*)Cp)[(size_t)gr * N + gc] = v + bias[gc] + res[(size_t)gr * N + gc];
                }
            }
}

// ======================= LayerNorm f32 -> bf16 (used for LN2) =======================
__global__ __launch_bounds__(256) void ln_kernel(
    const float* __restrict__ X, const float* __restrict__ G,
    const float* __restrict__ Bt, bf16_t* __restrict__ O)
{
    const int row = blockIdx.x, tid = threadIdx.x;
    const int wave = tid >> 6, lane = tid & 63;
    const size_t base = (size_t)row * 1024 + tid * 4;
    f32x4 xv = *(const f32x4*)&X[base];
    float s  = xv[0] + xv[1] + xv[2] + xv[3];
    float s2 = xv[0]*xv[0] + xv[1]*xv[1] + xv[2]*xv[2] + xv[3]*xv[3];
#pragma unroll
    for (int o = 1; o < 64; o <<= 1) { s += __shfl_xor(s, o); s2 += __shfl_xor(s2, o); }
    __shared__ float red[8];
    if (lane == 0) { red[wave] = s; red[wave + 4] = s2; }
    __syncthreads();
    s  = red[0] + red[1] + red[2] + red[3];
    s2 = red[4] + red[5] + red[6] + red[7];
    const float mu = s * (1.f / 1024.f);
    const float rs = rsqrtf(s2 * (1.f / 1024.f) - mu * mu + 1e-5f);
    f32x4 gv = *(const f32x4*)&G[tid * 4];
    f32x4 bv = *(const f32x4*)&Bt[tid * 4];
    u16x4 ov;
#pragma unroll
    for (int i = 0; i < 4; i++) ov[i] = f2bf((xv[i] - mu) * rs * gv[i] + bv[i]);
    *(u16x4*)&O[base] = ov;
}

// ======================= fused f32 -> bf16 convert (5 contiguous weight segments) =======================
__global__ __launch_bounds__(256) void cvt_all(
    const float* __restrict__ s0, const float* __restrict__ s1,
    const float* __restrict__ s2, const float* __restrict__ s3,
    const float* __restrict__ s4, bf16_t* __restrict__ dst,
    int n0, int n1, int n2, int n3, int n4)
{
    int i = (blockIdx.x * 256 + threadIdx.x) * 4;
    const float* s; int base;
    if (i < n0)                     { s = s0; base = 0; }
    else if (i < n0+n1)             { s = s1; base = n0; }
    else if (i < n0+n1+n2)          { s = s2; base = n0+n1; }
    else if (i < n0+n1+n2+n3)       { s = s3; base = n0+n1+n2; }
    else                            { s = s4; base = n0+n1+n2+n3; }
    f32x4 v = *(const f32x4*)&s[i - base];
    u16x4 o;
#pragma unroll
    for (int t = 0; t < 4; t++) o[t] = f2bf(v[t]);
    *(u16x4*)&dst[i] = o;
}

// ======================= banded softmax, window 256 (ALiBi + causal) — r7/r9 validated =======================
__global__ __launch_bounds__(256) void attn_p(
    const bf16_t* __restrict__ QK, bf16_t* __restrict__ P, int T)
{
    const int tid = threadIdx.x, w = tid >> 6, lane = tid & 63;
    const int lcol = lane & 15, krow = lane >> 4;
    const int qt = blockIdx.x;
    const int ntb = T >> 6;
    const int b = qt / ntb;
    const int r0 = (qt - b * ntb) << 6;
    const size_t g0 = (size_t)b * T + r0;
    const int jbase = r0 - 192;
    const float scale = 0.08838834764831845f;  // 128^-0.5

    __shared__ float lred[2][4][64];

    u16x8 qf[4][4];
#pragma unroll
    for (int mf = 0; mf < 4; mf++)
#pragma unroll
        for (int ks = 0; ks < 4; ks++)
            qf[mf][ks] = *(const u16x8*)&QK[(g0 + mf * 16 + lcol) * 256 + ks * 32 + krow * 8];

    f32x4 acc[4][4] = {};
    const size_t kbase = (size_t)b * T * 256 + 128;
#pragma unroll
    for (int ks = 0; ks < 4; ks++) {
        u16x8 kf[4];
#pragma unroll
        for (int nf = 0; nf < 4; nf++) {
            int jc = jbase + w * 64 + nf * 16 + lcol;
            int jr = jc < 0 ? 0 : jc;
            kf[nf] = *(const u16x8*)&QK[kbase + (size_t)jr * 256 + ks * 32 + krow * 8];
        }
#pragma unroll
        for (int mf = 0; mf < 4; mf++)
#pragma unroll
            for (int nf = 0; nf < 4; nf++)
                mfma16(acc[mf][nf], qf[mf][ks], kf[nf]);
    }

#pragma unroll
    for (int mf = 0; mf < 4; mf++)
#pragma unroll
        for (int j = 0; j < 4; j++) {
            const int i_ = r0 + mf * 16 + krow * 4 + j;
            float m = -1e30f;
#pragma unroll
            for (int nf = 0; nf < 4; nf++) {
                const int jc = jbase + w * 64 + nf * 16 + lcol;
                float sv = (jc >= 0 && jc <= i_) ? acc[mf][nf][j] * scale - (float)(i_ - jc) : -1e30f;
                acc[mf][nf][j] = sv;
                m = fmaxf(m, sv);
            }
#pragma unroll
            for (int o = 1; o < 16; o <<= 1) m = fmaxf(m, __shfl_xor(m, o));
            if (lcol == 0) lred[0][w][mf * 16 + krow * 4 + j] = m;
        }
    __syncthreads();

#pragma unroll
    for (int mf = 0; mf < 4; mf++)
#pragma unroll
        for (int j = 0; j < 4; j++) {
            const int rr = mf * 16 + krow * 4 + j;
            const float m = fmaxf(fmaxf(lred[0][0][rr], lred[0][1][rr]),
                                  fmaxf(lred[0][2][rr], lred[0][3][rr]));
            float sm = 0.f;
#pragma unroll
            for (int nf = 0; nf < 4; nf++) {
                float p = __expf(acc[mf][nf][j] - m);
                acc[mf][nf][j] = p;
                sm += p;
            }
#pragma unroll
            for (int o = 1; o < 16; o <<= 1) sm += __shfl_xor(sm, o);
            if (lcol == 0) lred[1][w][rr] = sm;
        }
    __syncthreads();

    float inv_l[4][4];
#pragma unroll
    for (int mf = 0; mf < 4; mf++)
#pragma unroll
        for (int j = 0; j < 4; j++) {
            const int rr = mf * 16 + krow * 4 + j;
            inv_l[mf][j] = 1.f / (lred[1][0][rr] + lred[1][1][rr] + lred[1][2][rr] + lred[1][3][rr]);
        }
#pragma unroll
    for (int mf = 0; mf < 4; mf++)
#pragma unroll
        for (int nf = 0; nf < 4; nf++)
#pragma unroll
            for (int j = 0; j < 4; j++) {
                const int rr = mf * 16 + krow * 4 + j;
                P[((size_t)qt * 64 + rr) * 256 + w * 64 + nf * 16 + lcol] =
                    f2bf(acc[mf][nf][j] * inv_l[mf][j]);
            }
}

// ======================= band PV: ctx = P @ h (K = 256) — r7/r9 validated =======================
__global__ __launch_bounds__(256) void pv_gemm(
    const bf16_t* __restrict__ P, const bf16_t* __restrict__ H,
    bf16_t* __restrict__ CTX, int T)
{
    alignas(16) __shared__ bf16_t sHt[128 * 40];
    const int tid = threadIdx.x, w = tid >> 6, lane = tid & 63;
    const int lcol = lane & 15, krow = lane >> 4;
    const int qt = blockIdx.x, d0 = blockIdx.y * 128;
    const int ntb = T >> 6, b = qt / ntb;
    const int r0 = (qt - b * ntb) << 6;
    const int jbase = r0 - 192;
    const int wm = (w >> 1) * 32, wn = (w & 1) * 64;
    const int kk = tid >> 3, seg = tid & 7;

    f32x4 acc[2][4] = {};
    for (int k0 = 0; k0 < 256; k0 += 32) {
        int j = jbase + k0 + kk;
        if (j < 0) j = 0;  // P is 0 there
        const bf16_t* hp = H + ((size_t)b * T + j) * 1024 + d0 + seg * 16;
        u16x8 v0 = *(const u16x8*)hp;
        u16x8 v1 = *(const u16x8*)(hp + 8);
        __syncthreads();
#pragma unroll
        for (int i = 0; i < 8; i++) {
            sHt[(seg * 16 + i) * 40 + kk]     = v0[i];
            sHt[(seg * 16 + 8 + i) * 40 + kk] = v1[i];
        }
        __syncthreads();
        u16x8 af[2], bfr[4];
#pragma unroll
        for (int mi = 0; mi < 2; mi++)
            af[mi] = *(const u16x8*)&P[((size_t)qt * 64 + wm + mi * 16 + lcol) * 256 + k0 + krow * 8];
#pragma unroll
        for (int ni = 0; ni < 4; ni++)
            bfr[ni] = *(const u16x8*)&sHt[(wn + ni * 16 + lcol) * 40 + krow * 8];
#pragma unroll
        for (int mi = 0; mi < 2; mi++)
#pragma unroll
            for (int ni = 0; ni < 4; ni++)
                mfma16(acc[mi][ni], af[mi], bfr[ni]);
    }
#pragma unroll
    for (int mi = 0; mi < 2; mi++)
#pragma unroll
        for (int ni = 0; ni < 4; ni++)
#pragma unroll
            for (int j = 0; j < 4; j++)
                CTX[((size_t)b * T + r0 + wm + mi * 16 + krow * 4 + j) * 1024 +
                    d0 + wn + ni * 16 + lcol] = f2bf(acc[mi][ni][j]);
}

// ======================= launch =======================
extern "C" void kernel_launch(void* const* d_in, const int* in_sizes, int n_in,
                              void* d_out, int out_size, void* d_ws, size_t ws_size,
                              hipStream_t stream)
{
    const float* x   = (const float*)d_in[0];
    const float* g1  = (const float*)d_in[1];
    const float* be1 = (const float*)d_in[2];
    const float* Wq  = (const float*)d_in[3];
    const float* Wk  = (const float*)d_in[4];
    const float* Wv  = (const float*)d_in[5];
    const float* g2  = (const float*)d_in[6];
    const float* be2 = (const float*)d_in[7];
    const float* W1  = (const float*)d_in[8];
    const float* b1  = (const float*)d_in[9];
    const float* W2  = (const float*)d_in[10];
    const float* b2  = (const float*)d_in[11];

    const int B = 4, T = 4096, D = 1024, DK = 128, F = 2048;
    const int BT = B * T;

    char* ws = (char*)d_ws;
    size_t off = 0;
    auto alloc = [&](size_t bytes) {
        void* p = ws + off;
        off += (bytes + 255) & ~(size_t)255;
        return p;
    };
    // NOTE: the 5 weight segments are contiguous; cvt_all writes them flat.
    bf16_t* wqk_b = (bf16_t*)alloc((size_t)2 * DK * D * 2);
    bf16_t* wv_b  = (bf16_t*)alloc((size_t)D * D * 2);
    bf16_t* w1_b  = (bf16_t*)alloc((size_t)F * D * 2);
    bf16_t* w2_b  = (bf16_t*)alloc((size_t)D * F * 2);
    bf16_t* h     = (bf16_t*)alloc((size_t)BT * D * 2);   // reused as h2
    bf16_t* qk    = (bf16_t*)alloc((size_t)BT * 256 * 2); // q | k
    bf16_t* P     = (bf16_t*)alloc((size_t)BT * 256 * 2); // window 256
    bf16_t* ctx   = (bf16_t*)alloc((size_t)BT * D * 2);
    bf16_t* ff    = (bf16_t*)alloc((size_t)BT * F * 2);
    if (ws_size < off) return;
    float* x2 = (float*)d_out;

    // weight conversions f32 -> bf16, one fused launch
    const int n0 = DK * D, n2 = D * D, n3 = F * D, n4 = D * F;
    const int ntot = n0 + n0 + n2 + n3 + n4;
    cvt_all<<<ntot / 1024, 256, 0, stream>>>(Wq, Wk, Wv, W1, W2, wqk_b,
                                             n0, n0, n2, n3, n4);

    // h = LN1(x)
    ln_kernel<<<BT, 256, 0, stream>>>(x, g1, be1, h);

    // [q|k] = h @ [Wq;Wk]^T   (fused, N=256)
    gemm_nt<0><<<dim3(BT / 128, 2), 256, 0, stream>>>(h, wqk_b, qk, nullptr, nullptr, BT, 256, D);

    // banded softmax (window 256) -> P, then ctx = P @ h
    attn_p<<<BT / 64, 256, 0, stream>>>(qk, P, T);
    pv_gemm<<<dim3(BT / 64, D / 128), 256, 0, stream>>>(P, h, ctx, T);

    // x2 = x + ctx @ Wv^T   (f32, into d_out)
    gemm256_nt<2><<<dim3(BT / 256, D / 256), 512, 0, stream>>>(ctx, wv_b, x2, nullptr, x, BT, D, D);

    // h2 = LN2(x2) (reuse h)
    ln_kernel<<<BT, 256, 0, stream>>>(x2, g2, be2, h);

    // ff = relu(h2 @ W1^T + b1)
    gemm256_nt<1><<<dim3(BT / 256, F / 256), 512, 0, stream>>>(h, w1_b, ff, b1, nullptr, BT, F, D);

    // out = x2 + ff @ W2^T + b2  (in-place on d_out)
    gemm256_nt<3><<<dim3(BT / 256, D / 256), 512, 0, stream>>>(ff, w2_b, x2, b2, x2, BT, D, F);
}